// Round 14
// baseline (135.644 us; speedup 1.0000x reference)
//
#include <hip/hip_runtime.h>
#include <hip/hip_bf16.h>

#define ROWS   8192
#define DIM    512
#define NCODES 8192
#define MARGIN 3.0f

using i32x4 = __attribute__((ext_vector_type(4))) int;
typedef unsigned char u8;

__device__ __forceinline__ void gload_lds16(const void* g, void* l) {
    __builtin_amdgcn_global_load_lds((const __attribute__((address_space(1))) void*)g,
                                     (__attribute__((address_space(3))) void*)l,
                                     16, 0, 0);
}

__device__ __forceinline__ unsigned int pack4(int a, int b, int c, int d) {
    return (a & 255) | ((b & 255) << 8) | ((c & 255) << 16) | ((unsigned)(d & 255) << 24);
}

// ---------- Kernel 1: LN+quant(H, per-row) | quant(E, per-64-row-chunk) ----------
__global__ __launch_bounds__(256) void prep_kernel(
    const float* __restrict__ x, const float* __restrict__ lw,
    const float* __restrict__ lb, const float* __restrict__ embd,
    float2* __restrict__ stats, float* __restrict__ sh, float* __restrict__ se,
    u8* __restrict__ Hq, u8* __restrict__ Eq)
{
    __shared__ float red[4];
    const int w    = threadIdx.x >> 6;
    const int lane = threadIdx.x & 63;
    const int b    = blockIdx.x;

    if (b < 2048) {                       // ---- H rows (per-row scale) ----
        const int row = b * 4 + w;
        const float* xr = x + (size_t)row * DIM + lane * 8;
        float4 v0 = *(const float4*)(xr);
        float4 v1 = *(const float4*)(xr + 4);
        float s = (v0.x + v0.y) + (v0.z + v0.w) + (v1.x + v1.y) + (v1.z + v1.w);
        float q = v0.x*v0.x + v0.y*v0.y + v0.z*v0.z + v0.w*v0.w
                + v1.x*v1.x + v1.y*v1.y + v1.z*v1.z + v1.w*v1.w;
        #pragma unroll
        for (int off = 1; off < 64; off <<= 1) {
            s += __shfl_xor(s, off);
            q += __shfl_xor(q, off);
        }
        float mu   = s * (1.0f / DIM);
        float var  = q * (1.0f / DIM) - mu * mu;
        float rstd = rsqrtf(var + 1e-5f);
        if (lane == 0) stats[row] = make_float2(mu, rstd);

        float4 w0 = *(const float4*)(lw + lane * 8);
        float4 w1 = *(const float4*)(lw + lane * 8 + 4);
        float4 b0 = *(const float4*)(lb + lane * 8);
        float4 b1 = *(const float4*)(lb + lane * 8 + 4);
        float hv[8] = {
            (v0.x - mu) * rstd * w0.x + b0.x, (v0.y - mu) * rstd * w0.y + b0.y,
            (v0.z - mu) * rstd * w0.z + b0.z, (v0.w - mu) * rstd * w0.w + b0.w,
            (v1.x - mu) * rstd * w1.x + b1.x, (v1.y - mu) * rstd * w1.y + b1.y,
            (v1.z - mu) * rstd * w1.z + b1.z, (v1.w - mu) * rstd * w1.w + b1.w };

        float am = 0.0f;
        #pragma unroll
        for (int j = 0; j < 8; ++j) am = fmaxf(am, fabsf(hv[j]));
        #pragma unroll
        for (int off = 1; off < 64; off <<= 1) am = fmaxf(am, __shfl_xor(am, off));
        const float inv = (am > 0.0f) ? (127.0f / am) : 0.0f;
        if (lane == 0) sh[row] = am * (1.0f / 127.0f);

        int qi[8];
        #pragma unroll
        for (int j = 0; j < 8; ++j) qi[j] = __float2int_rn(hv[j] * inv);
        uint2 p = make_uint2(pack4(qi[0], qi[1], qi[2], qi[3]),
                             pack4(qi[4], qi[5], qi[6], qi[7]));
        *(uint2*)(Hq + (size_t)row * DIM + lane * 8) = p;
    } else {                              // ---- E 64-row chunks (per-chunk scale) ----
        const int chunk = b - 2048;                    // 0..127
        const int row   = chunk * 64 + (threadIdx.x >> 2);
        const int off0  = (threadIdx.x & 3) * 128;
        const float* er = embd + (size_t)row * DIM + off0;

        float4 v[32];
        float am = 0.0f;
        #pragma unroll
        for (int j = 0; j < 32; ++j) {
            v[j] = *(const float4*)(er + j * 4);
            am = fmaxf(am, fmaxf(fmaxf(fabsf(v[j].x), fabsf(v[j].y)),
                                 fmaxf(fabsf(v[j].z), fabsf(v[j].w))));
        }
        #pragma unroll
        for (int off = 1; off < 64; off <<= 1) am = fmaxf(am, __shfl_xor(am, off));
        if (lane == 0) red[w] = am;
        __syncthreads();
        am = fmaxf(fmaxf(red[0], red[1]), fmaxf(red[2], red[3]));

        const float inv = (am > 0.0f) ? (127.0f / am) : 0.0f;
        if (threadIdx.x == 0) se[chunk] = am * (1.0f / 127.0f);

        u8* out = Eq + (size_t)row * DIM + off0;
        #pragma unroll
        for (int j = 0; j < 32; j += 4) {
            uint4 o;
            o.x = pack4(__float2int_rn(v[j+0].x*inv), __float2int_rn(v[j+0].y*inv),
                        __float2int_rn(v[j+0].z*inv), __float2int_rn(v[j+0].w*inv));
            o.y = pack4(__float2int_rn(v[j+1].x*inv), __float2int_rn(v[j+1].y*inv),
                        __float2int_rn(v[j+1].z*inv), __float2int_rn(v[j+1].w*inv));
            o.z = pack4(__float2int_rn(v[j+2].x*inv), __float2int_rn(v[j+2].y*inv),
                        __float2int_rn(v[j+2].z*inv), __float2int_rn(v[j+2].w*inv));
            o.w = pack4(__float2int_rn(v[j+3].x*inv), __float2int_rn(v[j+3].y*inv),
                        __float2int_rn(v[j+3].z*inv), __float2int_rn(v[j+3].w*inv));
            *(uint4*)(out + j * 4) = o;
        }
    }
}

// ---------- Kernel 2: A-in-REGISTERS i8 GEMM, B streamed, 4 barriers/block ----
// 256 blocks (1/CU), 512 threads = 8 waves; block = 512 rows x 512 cols.
// Per wave: 64 rows; af[4][8] (128 VGPR) holds ALL of A for the block's life
// (loaded once, direct from global — fragment addressing verified by R11).
// B: 4 nt-tiles of [128 col][512 K] = 64 KB, 2-slot LDS dbuf (128 KB),
// swizzle byte^=(col&7)<<4 (pre-swizzled source). Sync: ONE vmcnt(0)+barrier
// per nt (loads get ~4000 cyc slack). Per 64-col chunk: 32 ds_read + 128 MFMA
// (4:1 MFMA:read) + i32 packed-key fold. Candidates: top-2/(row,64chunk),
// 256/row — layout identical to R10.
__global__ __launch_bounds__(512, 2) void gemm_argmax_kernel(
    const u8* __restrict__ Hq, const u8* __restrict__ Eq,
    const float* __restrict__ sh, const float* __restrict__ se,
    float* __restrict__ pval, int* __restrict__ pidx)
{
    __shared__ __align__(16) u8 Bs[2][128 * DIM];   // 2 x 64 KB

    const int tid  = threadIdx.x;
    const int w    = tid >> 6;
    const int lane = tid & 63;
    const int r_   = lane & 15;
    const int g    = lane >> 4;

    // XCD map: xcd = bid&7 owns 2 col-groups (512 KB B L2-resident);
    // row-panels iterate fastest within the xcd.
    const int bid  = blockIdx.x;
    const int colg = ((bid & 7) << 1) | ((bid >> 3) & 1);   // 0..15
    const int rowp = bid >> 4;                              // 0..15
    const int r0   = rowp * 512;
    const int c0   = colg * 512;

    // ---- one-time A load to registers: af[m][kt] = Hq[r0+w*64+m*16+r_][kt*64+g*16]
    const u8* Abase = Hq + (size_t)(r0 + w * 64 + r_) * DIM + g * 16;
    i32x4 af[4][8];
    #pragma unroll
    for (int m = 0; m < 4; ++m)
        #pragma unroll
        for (int kt = 0; kt < 8; ++kt)
            af[m][kt] = *(const i32x4*)(Abase + (size_t)m * 16 * DIM + kt * 64);

    // ---- B staging geometry: 64 KB/tile, 8 gloads/thread (j=0..7).
    // dest d = j*8192 + tid*16 -> dcol_row = j*16 + (tid>>5), dk = (tid&31)*16.
    // inverse-swizzled SOURCE k byte = dk ^ ((drow&7)<<4).
    const int sdrow = (tid >> 5) & 1 ? 0 : 0; (void)sdrow;
    const int drow_lo = tid >> 5;              // 0..15 (w*2 + lane>>5)
    const int dk      = (tid & 31) * 16;
    const u8* sB = Eq + (size_t)(c0 + drow_lo) * DIM;   // + (nt*128 + j*16)*DIM
    const int ub = tid * 16;                             // + j*8192

#define STAGE_B(NT, SL) do {                                              \
        _Pragma("unroll")                                                 \
        for (int j = 0; j < 8; ++j) {                                     \
            const int drow = j * 16 + drow_lo;                            \
            gload_lds16(sB + ((size_t)(NT) * 128 + j * 16) * DIM          \
                           + (dk ^ ((drow & 7) << 4)),                    \
                        &Bs[SL][j * 8192 + ub]);                          \
        }                                                                 \
    } while (0)
#define MF(M, N, AV, BV) \
        acc[M][N] = __builtin_amdgcn_mfma_i32_16x16x64_i8(AV, BV, acc[M][N], 0, 0, 0)

    STAGE_B(0, 0);
    asm volatile("s_waitcnt vmcnt(0)" ::: "memory");
    __builtin_amdgcn_s_barrier();

    const int fldB = (r_ & 7) << 4;

    for (int nt = 0; nt < 4; ++nt) {
        const u8* Bp = &Bs[nt & 1][0];
        if (nt < 3) STAGE_B(nt + 1, (nt + 1) & 1);

        #pragma unroll
        for (int ch = 0; ch < 2; ++ch) {
            i32x4 acc[4][4];
            #pragma unroll
            for (int m = 0; m < 4; ++m)
                #pragma unroll
                for (int n = 0; n < 4; ++n) acc[m][n] = (i32x4){0, 0, 0, 0};

            // B read base: col = ch*64 + n*16 + r_, kbyte = kt*64 + g*16 (^swz)
            const int bb = (ch * 64 + r_) * 512;

            #pragma unroll
            for (int kt = 0; kt < 8; ++kt) {
                const int ko = (kt * 64 + g * 16) ^ fldB;
                i32x4 b0 = *(const i32x4*)(Bp + bb + 0 * 8192 + ko);
                i32x4 b1 = *(const i32x4*)(Bp + bb + 1 * 8192 + ko);
                i32x4 b2 = *(const i32x4*)(Bp + bb + 2 * 8192 + ko);
                i32x4 b3 = *(const i32x4*)(Bp + bb + 3 * 8192 + ko);
                __builtin_amdgcn_s_setprio(1);
                MF(0, 0, af[0][kt], b0); MF(0, 1, af[0][kt], b1);
                MF(0, 2, af[0][kt], b2); MF(0, 3, af[0][kt], b3);
                MF(1, 0, af[1][kt], b0); MF(1, 1, af[1][kt], b1);
                MF(1, 2, af[1][kt], b2); MF(1, 3, af[1][kt], b3);
                MF(2, 0, af[2][kt], b0); MF(2, 1, af[2][kt], b1);
                MF(2, 2, af[2][kt], b2); MF(2, 3, af[2][kt], b3);
                MF(3, 0, af[3][kt], b0); MF(3, 1, af[3][kt], b1);
                MF(3, 2, af[3][kt], b2); MF(3, 3, af[3][kt], b3);
                __builtin_amdgcn_s_setprio(0);
            }

            // ---- fold chunk into top-2 (i32 packed keys), store ----
            const int chunk = colg * 8 + nt * 2 + ch;   // global col/64
            const int cb    = chunk * 64;
            const float se_ch = se[chunk];
            #pragma unroll
            for (int m = 0; m < 4; ++m) {
                #pragma unroll
                for (int reg = 0; reg < 4; ++reg) {
                    int ka = (acc[m][0][reg] << 7) | (63 - r_);
                    int kb = (acc[m][1][reg] << 7) | (47 - r_);
                    int kc = (acc[m][2][reg] << 7) | (31 - r_);
                    int kd = (acc[m][3][reg] << 7) | (15 - r_);
                    int m1 = max(ka, kb), n1 = min(ka, kb);
                    int m2 = max(kc, kd), n2 = min(kc, kd);
                    int k1 = max(m1, m2);
                    int k2 = max(min(m1, m2), max(n1, n2));
                    #pragma unroll
                    for (int off = 1; off < 16; off <<= 1) {
                        int o1 = __shfl_xor(k1, off);
                        int o2 = __shfl_xor(k2, off);
                        k2 = max(max(k2, o2), min(k1, o1));
                        k1 = max(k1, o1);
                    }
                    if (r_ == 0) {
                        const int row = r0 + w * 64 + m * 16 + g * 4 + reg;
                        const float sc = sh[row];
                        const size_t base = (size_t)row * 256 + chunk * 2;
                        pval[base]     = (float)(k1 >> 7) * (sc * se_ch);
                        pval[base + 1] = (float)(k2 >> 7) * (sc * se_ch);
                        pidx[base]     = cb + 63 - (k1 & 63);
                        pidx[base + 1] = cb + 63 - (k2 & 63);
                    }
                }
            }
        }

        if (nt < 3) {
            asm volatile("s_waitcnt vmcnt(0)" ::: "memory");  // B(nt+1) landed
            __builtin_amdgcn_s_barrier();
        }
    }

#undef MF
#undef STAGE_B
}

// ---------- Kernel 3: exact fp32 re-check of candidates + gather ----------
__global__ __launch_bounds__(256) void finalize_kernel(
    const float* __restrict__ x, const float* __restrict__ lw,
    const float* __restrict__ lb, const float* __restrict__ embd,
    const float2* __restrict__ stats,
    const float* __restrict__ pval, const int* __restrict__ pidx,
    float* __restrict__ outq, float* __restrict__ outi)
{
    const int w    = threadIdx.x >> 6;
    const int lane = threadIdx.x & 63;
    const int row  = blockIdx.x * 4 + w;

    const float4 cv = *(const float4*)&pval[(size_t)row * 256 + lane * 4];
    const int4   ci = *(const int4*)  &pidx[(size_t)row * 256 + lane * 4];
    float vv[4] = { cv.x, cv.y, cv.z, cv.w };
    int   ii[4] = { ci.x, ci.y, ci.z, ci.w };

    float M = fmaxf(fmaxf(vv[0], vv[1]), fmaxf(vv[2], vv[3]));
    #pragma unroll
    for (int off = 1; off < 64; off <<= 1) M = fmaxf(M, __shfl_xor(M, off));
    const float T = M - MARGIN;

    const float2 st = stats[row];
    const float mu = st.x, rstd = st.y;
    const float* xr = x + (size_t)row * DIM + lane * 8;
    float4 x0 = *(const float4*)(xr);
    float4 x1 = *(const float4*)(xr + 4);
    float4 w0 = *(const float4*)(lw + lane * 8);
    float4 w1 = *(const float4*)(lw + lane * 8 + 4);
    float4 b0 = *(const float4*)(lb + lane * 8);
    float4 b1 = *(const float4*)(lb + lane * 8 + 4);
    float h[8] = {
        (x0.x - mu) * rstd * w0.x + b0.x, (x0.y - mu) * rstd * w0.y + b0.y,
        (x0.z - mu) * rstd * w0.z + b0.z, (x0.w - mu) * rstd * w0.w + b0.w,
        (x1.x - mu) * rstd * w1.x + b1.x, (x1.y - mu) * rstd * w1.y + b1.y,
        (x1.z - mu) * rstd * w1.z + b1.z, (x1.w - mu) * rstd * w1.w + b1.w };

    float bestv = -3.4e38f; int besti = 0x7fffffff;
    #pragma unroll
    for (int s = 0; s < 4; ++s) {
        unsigned long long msk = __ballot(vv[s] >= T);
        while (msk) {
            const int L = __ffsll(msk) - 1;
            msk &= msk - 1;
            const int cand = __shfl(ii[s], L);
            const float* er = embd + (size_t)cand * DIM + lane * 8;
            float4 e0 = *(const float4*)er;
            float4 e1 = *(const float4*)(er + 4);
            float d = h[0]*e0.x + h[1]*e0.y + h[2]*e0.z + h[3]*e0.w
                    + h[4]*e1.x + h[5]*e1.y + h[6]*e1.z + h[7]*e1.w;
            #pragma unroll
            for (int off = 1; off < 64; off <<= 1) d += __shfl_xor(d, off);
            if (d > bestv || (d == bestv && cand < besti)) { bestv = d; besti = cand; }
        }
    }

    const float* er = embd + (size_t)besti * DIM + lane * 8;
    float4 q0 = *(const float4*)er;
    float4 q1 = *(const float4*)(er + 4);
    float* qr = outq + (size_t)row * DIM + lane * 8;
    *(float4*)(qr)     = q0;
    *(float4*)(qr + 4) = q1;
    if (lane == 0) outi[row] = (float)besti;
}

extern "C" void kernel_launch(void* const* d_in, const int* in_sizes, int n_in,
                              void* d_out, int out_size, void* d_ws, size_t ws_size,
                              hipStream_t stream) {
    const float* x    = (const float*)d_in[0];
    const float* lnw  = (const float*)d_in[1];
    const float* lnb  = (const float*)d_in[2];
    const float* embd = (const float*)d_in[3];

    float* outq = (float*)d_out;
    float* outi = outq + (size_t)ROWS * DIM;

    char* ws = (char*)d_ws;
    float2* stats = (float2*)ws;                                  // 64 KiB
    float*  sh    = (float*)(ws + (1 << 16));                     // 32 KiB
    float*  se    = (float*)(ws + (1 << 16) + (1 << 15));         // 512 B used
    u8*     Hq    = (u8*)(ws + (1 << 17));                        // 4 MiB
    u8*     Eq    = (u8*)(ws + (1 << 17) + (4 << 20));            // 4 MiB
    float*  pval  = (float*)(ws + (1 << 17) + (8 << 20));         // 8 MiB
    int*    pidx  = (int*)  (ws + (1 << 17) + (16 << 20));        // 8 MiB

    prep_kernel<<<2176, 256, 0, stream>>>(x, lnw, lnb, embd, stats, sh, se, Hq, Eq);

    gemm_argmax_kernel<<<256, 512, 0, stream>>>(Hq, Eq, sh, se, pval, pidx);

    finalize_kernel<<<ROWS / 4, 256, 0, stream>>>(x, lnw, lnb, embd, stats,
                                                  pval, pidx, outq, outi);
}

// Round 15
// 133.594 us; speedup vs baseline: 1.0153x; 1.0153x over previous
//
#include <hip/hip_runtime.h>
#include <hip/hip_bf16.h>

#define ROWS   8192
#define DIM    512
#define NCODES 8192
#define BM     256
#define BN     128
#define BK     64                     // i8 K-tile
#define NT     (DIM / BK)             // 8 K-tiles
#define MARGIN 3.0f

using i32x4 = __attribute__((ext_vector_type(4))) int;
typedef unsigned char u8;

__device__ __forceinline__ void gload_lds16(const void* g, void* l) {
    __builtin_amdgcn_global_load_lds((const __attribute__((address_space(1))) void*)g,
                                     (__attribute__((address_space(3))) void*)l,
                                     16, 0, 0);
}

__device__ __forceinline__ unsigned int pack4(int a, int b, int c, int d) {
    return (a & 255) | ((b & 255) << 8) | ((c & 255) << 16) | ((unsigned)(d & 255) << 24);
}

// ---------- Kernel 1: LN+quant(H, per-row) | quant(E, per-64-row-chunk) ----------
__global__ __launch_bounds__(256) void prep_kernel(
    const float* __restrict__ x, const float* __restrict__ lw,
    const float* __restrict__ lb, const float* __restrict__ embd,
    float2* __restrict__ stats, float* __restrict__ sh, float* __restrict__ se,
    u8* __restrict__ Hq, u8* __restrict__ Eq)
{
    __shared__ float red[4];
    const int w    = threadIdx.x >> 6;
    const int lane = threadIdx.x & 63;
    const int b    = blockIdx.x;

    if (b < 2048) {                       // ---- H rows (per-row scale) ----
        const int row = b * 4 + w;
        const float* xr = x + (size_t)row * DIM + lane * 8;
        float4 v0 = *(const float4*)(xr);
        float4 v1 = *(const float4*)(xr + 4);
        float s = (v0.x + v0.y) + (v0.z + v0.w) + (v1.x + v1.y) + (v1.z + v1.w);
        float q = v0.x*v0.x + v0.y*v0.y + v0.z*v0.z + v0.w*v0.w
                + v1.x*v1.x + v1.y*v1.y + v1.z*v1.z + v1.w*v1.w;
        #pragma unroll
        for (int off = 1; off < 64; off <<= 1) {
            s += __shfl_xor(s, off);
            q += __shfl_xor(q, off);
        }
        float mu   = s * (1.0f / DIM);
        float var  = q * (1.0f / DIM) - mu * mu;
        float rstd = rsqrtf(var + 1e-5f);
        if (lane == 0) stats[row] = make_float2(mu, rstd);

        float4 w0 = *(const float4*)(lw + lane * 8);
        float4 w1 = *(const float4*)(lw + lane * 8 + 4);
        float4 b0 = *(const float4*)(lb + lane * 8);
        float4 b1 = *(const float4*)(lb + lane * 8 + 4);
        float hv[8] = {
            (v0.x - mu) * rstd * w0.x + b0.x, (v0.y - mu) * rstd * w0.y + b0.y,
            (v0.z - mu) * rstd * w0.z + b0.z, (v0.w - mu) * rstd * w0.w + b0.w,
            (v1.x - mu) * rstd * w1.x + b1.x, (v1.y - mu) * rstd * w1.y + b1.y,
            (v1.z - mu) * rstd * w1.z + b1.z, (v1.w - mu) * rstd * w1.w + b1.w };

        float am = 0.0f;
        #pragma unroll
        for (int j = 0; j < 8; ++j) am = fmaxf(am, fabsf(hv[j]));
        #pragma unroll
        for (int off = 1; off < 64; off <<= 1) am = fmaxf(am, __shfl_xor(am, off));
        const float inv = (am > 0.0f) ? (127.0f / am) : 0.0f;
        if (lane == 0) sh[row] = am * (1.0f / 127.0f);

        int qi[8];
        #pragma unroll
        for (int j = 0; j < 8; ++j) qi[j] = __float2int_rn(hv[j] * inv);
        uint2 p = make_uint2(pack4(qi[0], qi[1], qi[2], qi[3]),
                             pack4(qi[4], qi[5], qi[6], qi[7]));
        *(uint2*)(Hq + (size_t)row * DIM + lane * 8) = p;
    } else {                              // ---- E 64-row chunks (per-chunk scale) ----
        const int chunk = b - 2048;                    // 0..127
        const int row   = chunk * 64 + (threadIdx.x >> 2);
        const int off0  = (threadIdx.x & 3) * 128;
        const float* er = embd + (size_t)row * DIM + off0;

        float4 v[32];
        float am = 0.0f;
        #pragma unroll
        for (int j = 0; j < 32; ++j) {
            v[j] = *(const float4*)(er + j * 4);
            am = fmaxf(am, fmaxf(fmaxf(fabsf(v[j].x), fabsf(v[j].y)),
                                 fmaxf(fabsf(v[j].z), fabsf(v[j].w))));
        }
        #pragma unroll
        for (int off = 1; off < 64; off <<= 1) am = fmaxf(am, __shfl_xor(am, off));
        if (lane == 0) red[w] = am;
        __syncthreads();
        am = fmaxf(fmaxf(red[0], red[1]), fmaxf(red[2], red[3]));

        const float inv = (am > 0.0f) ? (127.0f / am) : 0.0f;
        if (threadIdx.x == 0) se[chunk] = am * (1.0f / 127.0f);

        u8* out = Eq + (size_t)row * DIM + off0;
        #pragma unroll
        for (int j = 0; j < 32; j += 4) {
            uint4 o;
            o.x = pack4(__float2int_rn(v[j+0].x*inv), __float2int_rn(v[j+0].y*inv),
                        __float2int_rn(v[j+0].z*inv), __float2int_rn(v[j+0].w*inv));
            o.y = pack4(__float2int_rn(v[j+1].x*inv), __float2int_rn(v[j+1].y*inv),
                        __float2int_rn(v[j+1].z*inv), __float2int_rn(v[j+1].w*inv));
            o.z = pack4(__float2int_rn(v[j+2].x*inv), __float2int_rn(v[j+2].y*inv),
                        __float2int_rn(v[j+2].z*inv), __float2int_rn(v[j+2].w*inv));
            o.w = pack4(__float2int_rn(v[j+3].x*inv), __float2int_rn(v[j+3].y*inv),
                        __float2int_rn(v[j+3].z*inv), __float2int_rn(v[j+3].w*inv));
            *(uint4*)(out + j * 4) = o;
        }
    }
}

// ---------- Kernel 2: 256x128 i8 GEMM — A direct-to-reg, B via 4-slot LDS ----
// R10 skeleton with A's LDS round-trip removed (A fragments are per-wave-pair
// anyway; LDS traffic/tile drops 72->24 KB, the R10 binding pipe). B keeps the
// verified swizzle/staging in a 4-slot ring (stage target's readers are 2
// barriers back -> WAR-safe). vmcnt counts include the 8 per-wave A loads:
// steady 12 (=A(t)8+B(t+1)2+B(t+2)2), tail 10, 8.
__global__ __launch_bounds__(256, 2) void gemm_argmax_kernel(
    const u8* __restrict__ Hq, const u8* __restrict__ Eq,
    const float* __restrict__ sh, const float* __restrict__ se,
    float* __restrict__ pval, int* __restrict__ pidx)
{
    __shared__ __align__(16) u8 Bs[4][BN * BK];   // 4 x 8 KB

    const int tid  = threadIdx.x;
    const int w    = tid >> 6;
    const int lane = tid & 63;
    const int r_   = lane & 15;
    const int g    = lane >> 4;
    const int wr   = w >> 1;          // row half (0,1) -> 128 rows
    const int wc   = w & 1;           // col half (0,1) -> 64 cols

    // T1: XCD map. xcd = bid&7 owns 4 row-panels x all 64 col-tiles, col-major.
    const int bid  = blockIdx.x;
    const int trow = ((bid & 7) << 2) | ((bid >> 3) & 3);   // 0..31
    const int tcol = bid >> 5;                              // 0..63
    const int r0 = trow * BM;
    const int n0 = tcol * BN;

    // ---- B staging geometry (R10-verified, T2 swizzle) ----
    const int db0 = (w * 2 + 0) * 16 + (lane >> 2);
    const int db1 = (w * 2 + 1) * 16 + (lane >> 2);
    const int lc  = (lane & 3) * 16;
    const u8* sB0 = Eq + (size_t)(n0 + db0) * DIM + (lc ^ (((db0 >> 1) & 3) << 4));
    const u8* sB1 = Eq + (size_t)(n0 + db1) * DIM + (lc ^ (((db1 >> 1) & 3) << 4));
    const int ub0 = (w * 2 + 0) * 1024, ub1 = (w * 2 + 1) * 1024;

    // swizzled ds_read base for B (byte offset within a slot)
    const int swz   = ((r_ >> 1) & 3) << 4;
    const int bbase = (wc * 64 + r_) * 64 + ((g * 16) ^ swz);   // + n*1024

    // ---- A direct-load base: af[m] = Hq[r0+wr*128+m*16+r_][kt*64+g*16..+15]
    // (fragment addressing verified end-to-end by R11; 64B-coalesced)
    const u8* Ab = Hq + (size_t)(r0 + wr * 128 + r_) * DIM + g * 16;

    i32x4 acc[8][4];
    #pragma unroll
    for (int m = 0; m < 8; ++m)
        #pragma unroll
        for (int n = 0; n < 4; ++n) acc[m][n] = (i32x4){0, 0, 0, 0};

    i32x4 af[8];

#define STAGE_B(T) do {                                             \
        const int _ko = (T) * BK;                                   \
        gload_lds16(sB0 + _ko, &Bs[(T) & 3][ub0]);                  \
        gload_lds16(sB1 + _ko, &Bs[(T) & 3][ub1]);                  \
    } while (0)
#define LOAD_A(KT) do {                                             \
        const int _ko = (KT) * BK;                                  \
        af[0] = *(const i32x4*)(Ab + 0 * 8192 + _ko);               \
        af[1] = *(const i32x4*)(Ab + 1 * 8192 + _ko);               \
        af[2] = *(const i32x4*)(Ab + 2 * 8192 + _ko);               \
        af[3] = *(const i32x4*)(Ab + 3 * 8192 + _ko);               \
        af[4] = *(const i32x4*)(Ab + 4 * 8192 + _ko);               \
        af[5] = *(const i32x4*)(Ab + 5 * 8192 + _ko);               \
        af[6] = *(const i32x4*)(Ab + 6 * 8192 + _ko);               \
        af[7] = *(const i32x4*)(Ab + 7 * 8192 + _ko);               \
    } while (0)
#define MF(M, N, AV, BV) \
        acc[M][N] = __builtin_amdgcn_mfma_i32_16x16x64_i8(AV, BV, acc[M][N], 0, 0, 0)

#define K_TILE(T, VMSTR, DOSTG, DOA) do {                           \
        if (DOSTG) STAGE_B((T) + 2);                                \
        asm volatile("s_waitcnt vmcnt(" VMSTR ")" ::: "memory");    \
        __builtin_amdgcn_s_barrier();                               \
        const u8* Bp = &Bs[(T) & 3][0];                             \
        i32x4 b0 = *(const i32x4*)(Bp + bbase + 0 * 1024);          \
        i32x4 b1 = *(const i32x4*)(Bp + bbase + 1 * 1024);          \
        i32x4 b2 = *(const i32x4*)(Bp + bbase + 2 * 1024);          \
        i32x4 b3 = *(const i32x4*)(Bp + bbase + 3 * 1024);          \
        __builtin_amdgcn_s_setprio(1);                              \
        MF(0, 0, af[0], b0); MF(0, 1, af[0], b1); MF(0, 2, af[0], b2); MF(0, 3, af[0], b3); \
        MF(1, 0, af[1], b0); MF(1, 1, af[1], b1); MF(1, 2, af[1], b2); MF(1, 3, af[1], b3); \
        MF(2, 0, af[2], b0); MF(2, 1, af[2], b1); MF(2, 2, af[2], b2); MF(2, 3, af[2], b3); \
        MF(3, 0, af[3], b0); MF(3, 1, af[3], b1); MF(3, 2, af[3], b2); MF(3, 3, af[3], b3); \
        MF(4, 0, af[4], b0); MF(4, 1, af[4], b1); MF(4, 2, af[4], b2); MF(4, 3, af[4], b3); \
        MF(5, 0, af[5], b0); MF(5, 1, af[5], b1); MF(5, 2, af[5], b2); MF(5, 3, af[5], b3); \
        MF(6, 0, af[6], b0); MF(6, 1, af[6], b1); MF(6, 2, af[6], b2); MF(6, 3, af[6], b3); \
        MF(7, 0, af[7], b0); MF(7, 1, af[7], b1); MF(7, 2, af[7], b2); MF(7, 3, af[7], b3); \
        __builtin_amdgcn_s_setprio(0);                              \
        if (DOA) LOAD_A((T) + 1);                                   \
    } while (0)

    // prologue: B0->slot0, B1->slot1 staged; A(0) loading into regs
    STAGE_B(0);
    STAGE_B(1);
    LOAD_A(0);

    K_TILE(0, "12", 1, 1);   // stages B2->s2, loads A1
    K_TILE(1, "12", 1, 1);   // B3->s3, A2
    K_TILE(2, "12", 1, 1);   // B4->s0 (read t=0, 2 barriers back), A3
    K_TILE(3, "12", 1, 1);   // B5->s1, A4
    K_TILE(4, "12", 1, 1);   // B6->s2, A5
    K_TILE(5, "12", 1, 1);   // B7->s3, A6
    K_TILE(6, "10", 0, 1);   // no stage; A7
    K_TILE(7, "8",  0, 0);   // drain B7

#undef K_TILE
#undef MF
#undef LOAD_A
#undef STAGE_B

    // ---- epilogue: pure-i32 packed-key top-2 per (row, 64-col chunk) ----
    const int cb    = n0 + wc * 64;
    const float se_ch = se[tcol * 2 + wc];
    #pragma unroll
    for (int m = 0; m < 8; ++m) {
        const float4 sc4 = *(const float4*)&sh[r0 + wr * 128 + m * 16 + g * 4];
        #pragma unroll
        for (int reg = 0; reg < 4; ++reg) {
            int ka = (acc[m][0][reg] << 7) | (63 - r_);
            int kb = (acc[m][1][reg] << 7) | (47 - r_);
            int kc = (acc[m][2][reg] << 7) | (31 - r_);
            int kd = (acc[m][3][reg] << 7) | (15 - r_);
            int m1 = max(ka, kb), n1 = min(ka, kb);
            int m2 = max(kc, kd), n2 = min(kc, kd);
            int k1 = max(m1, m2);
            int k2 = max(min(m1, m2), max(n1, n2));
            #pragma unroll
            for (int off = 1; off < 16; off <<= 1) {
                int b1 = __shfl_xor(k1, off);
                int b2 = __shfl_xor(k2, off);
                k2 = max(max(k2, b2), min(k1, b1));
                k1 = max(k1, b1);
            }
            if (r_ == 0) {
                const float sc = (reg == 0) ? sc4.x : (reg == 1) ? sc4.y
                                 : (reg == 2) ? sc4.z : sc4.w;
                const int row = r0 + wr * 128 + m * 16 + g * 4 + reg;
                const size_t base = (size_t)row * 256 + (tcol * 2 + wc) * 2;
                pval[base]     = (float)(k1 >> 7) * (sc * se_ch);
                pval[base + 1] = (float)(k2 >> 7) * (sc * se_ch);
                pidx[base]     = cb + 63 - (k1 & 63);
                pidx[base + 1] = cb + 63 - (k2 & 63);
            }
        }
    }
}

// ---------- Kernel 3: exact fp32 re-check of candidates + gather ----------
__global__ __launch_bounds__(256) void finalize_kernel(
    const float* __restrict__ x, const float* __restrict__ lw,
    const float* __restrict__ lb, const float* __restrict__ embd,
    const float2* __restrict__ stats,
    const float* __restrict__ pval, const int* __restrict__ pidx,
    float* __restrict__ outq, float* __restrict__ outi)
{
    const int w    = threadIdx.x >> 6;
    const int lane = threadIdx.x & 63;
    const int row  = blockIdx.x * 4 + w;

    const float4 cv = *(const float4*)&pval[(size_t)row * 256 + lane * 4];
    const int4   ci = *(const int4*)  &pidx[(size_t)row * 256 + lane * 4];
    float vv[4] = { cv.x, cv.y, cv.z, cv.w };
    int   ii[4] = { ci.x, ci.y, ci.z, ci.w };

    float M = fmaxf(fmaxf(vv[0], vv[1]), fmaxf(vv[2], vv[3]));
    #pragma unroll
    for (int off = 1; off < 64; off <<= 1) M = fmaxf(M, __shfl_xor(M, off));
    const float T = M - MARGIN;

    const float2 st = stats[row];
    const float mu = st.x, rstd = st.y;
    const float* xr = x + (size_t)row * DIM + lane * 8;
    float4 x0 = *(const float4*)(xr);
    float4 x1 = *(const float4*)(xr + 4);
    float4 w0 = *(const float4*)(lw + lane * 8);
    float4 w1 = *(const float4*)(lw + lane * 8 + 4);
    float4 b0 = *(const float4*)(lb + lane * 8);
    float4 b1 = *(const float4*)(lb + lane * 8 + 4);
    float h[8] = {
        (x0.x - mu) * rstd * w0.x + b0.x, (x0.y - mu) * rstd * w0.y + b0.y,
        (x0.z - mu) * rstd * w0.z + b0.z, (x0.w - mu) * rstd * w0.w + b0.w,
        (x1.x - mu) * rstd * w1.x + b1.x, (x1.y - mu) * rstd * w1.y + b1.y,
        (x1.z - mu) * rstd * w1.z + b1.z, (x1.w - mu) * rstd * w1.w + b1.w };

    float bestv = -3.4e38f; int besti = 0x7fffffff;
    #pragma unroll
    for (int s = 0; s < 4; ++s) {
        unsigned long long msk = __ballot(vv[s] >= T);
        while (msk) {
            const int L = __ffsll(msk) - 1;
            msk &= msk - 1;
            const int cand = __shfl(ii[s], L);
            const float* er = embd + (size_t)cand * DIM + lane * 8;
            float4 e0 = *(const float4*)er;
            float4 e1 = *(const float4*)(er + 4);
            float d = h[0]*e0.x + h[1]*e0.y + h[2]*e0.z + h[3]*e0.w
                    + h[4]*e1.x + h[5]*e1.y + h[6]*e1.z + h[7]*e1.w;
            #pragma unroll
            for (int off = 1; off < 64; off <<= 1) d += __shfl_xor(d, off);
            if (d > bestv || (d == bestv && cand < besti)) { bestv = d; besti = cand; }
        }
    }

    const float* er = embd + (size_t)besti * DIM + lane * 8;
    float4 q0 = *(const float4*)er;
    float4 q1 = *(const float4*)(er + 4);
    float* qr = outq + (size_t)row * DIM + lane * 8;
    *(float4*)(qr)     = q0;
    *(float4*)(qr + 4) = q1;
    if (lane == 0) outi[row] = (float)besti;
}

extern "C" void kernel_launch(void* const* d_in, const int* in_sizes, int n_in,
                              void* d_out, int out_size, void* d_ws, size_t ws_size,
                              hipStream_t stream) {
    const float* x    = (const float*)d_in[0];
    const float* lnw  = (const float*)d_in[1];
    const float* lnb  = (const float*)d_in[2];
    const float* embd = (const float*)d_in[3];

    float* outq = (float*)d_out;
    float* outi = outq + (size_t)ROWS * DIM;

    char* ws = (char*)d_ws;
    float2* stats = (float2*)ws;                                  // 64 KiB
    float*  sh    = (float*)(ws + (1 << 16));                     // 32 KiB
    float*  se    = (float*)(ws + (1 << 16) + (1 << 15));         // 512 B used
    u8*     Hq    = (u8*)(ws + (1 << 17));                        // 4 MiB
    u8*     Eq    = (u8*)(ws + (1 << 17) + (4 << 20));            // 4 MiB
    float*  pval  = (float*)(ws + (1 << 17) + (8 << 20));         // 8 MiB
    int*    pidx  = (int*)  (ws + (1 << 17) + (16 << 20));        // 8 MiB

    prep_kernel<<<2176, 256, 0, stream>>>(x, lnw, lnb, embd, stats, sh, se, Hq, Eq);

    gemm_argmax_kernel<<<2048, 256, 0, stream>>>(Hq, Eq, sh, se, pval, pidx);

    finalize_kernel<<<ROWS / 4, 256, 0, stream>>>(x, lnw, lnb, embd, stats,
                                                  pval, pidx, outq, outi);
}

// Round 16
// 105.889 us; speedup vs baseline: 1.2810x; 1.2616x over previous
//
#include <hip/hip_runtime.h>
#include <hip/hip_bf16.h>

#define ROWS   8192
#define DIM    512
#define NCODES 8192
#define BM     256
#define BN     128
#define BK     64                     // i8 K-tile
#define NT     (DIM / BK)             // 8 K-tiles
#define MARGIN 3.0f

using i32x4 = __attribute__((ext_vector_type(4))) int;
typedef unsigned char u8;

__device__ __forceinline__ void gload_lds16(const void* g, void* l) {
    __builtin_amdgcn_global_load_lds((const __attribute__((address_space(1))) void*)g,
                                     (__attribute__((address_space(3))) void*)l,
                                     16, 0, 0);
}

__device__ __forceinline__ unsigned int pack4(int a, int b, int c, int d) {
    return (a & 255) | ((b & 255) << 8) | ((c & 255) << 16) | ((unsigned)(d & 255) << 24);
}

// ---------- Kernel 1: LN+quant(H, per-row) | quant(E, per-64-row-chunk) ----------
__global__ __launch_bounds__(256) void prep_kernel(
    const float* __restrict__ x, const float* __restrict__ lw,
    const float* __restrict__ lb, const float* __restrict__ embd,
    float2* __restrict__ stats, float* __restrict__ sh, float* __restrict__ se,
    u8* __restrict__ Hq, u8* __restrict__ Eq)
{
    __shared__ float red[4];
    const int w    = threadIdx.x >> 6;
    const int lane = threadIdx.x & 63;
    const int b    = blockIdx.x;

    if (b < 2048) {                       // ---- H rows (per-row scale) ----
        const int row = b * 4 + w;
        const float* xr = x + (size_t)row * DIM + lane * 8;
        float4 v0 = *(const float4*)(xr);
        float4 v1 = *(const float4*)(xr + 4);
        float s = (v0.x + v0.y) + (v0.z + v0.w) + (v1.x + v1.y) + (v1.z + v1.w);
        float q = v0.x*v0.x + v0.y*v0.y + v0.z*v0.z + v0.w*v0.w
                + v1.x*v1.x + v1.y*v1.y + v1.z*v1.z + v1.w*v1.w;
        #pragma unroll
        for (int off = 1; off < 64; off <<= 1) {
            s += __shfl_xor(s, off);
            q += __shfl_xor(q, off);
        }
        float mu   = s * (1.0f / DIM);
        float var  = q * (1.0f / DIM) - mu * mu;
        float rstd = rsqrtf(var + 1e-5f);
        if (lane == 0) stats[row] = make_float2(mu, rstd);

        float4 w0 = *(const float4*)(lw + lane * 8);
        float4 w1 = *(const float4*)(lw + lane * 8 + 4);
        float4 b0 = *(const float4*)(lb + lane * 8);
        float4 b1 = *(const float4*)(lb + lane * 8 + 4);
        float hv[8] = {
            (v0.x - mu) * rstd * w0.x + b0.x, (v0.y - mu) * rstd * w0.y + b0.y,
            (v0.z - mu) * rstd * w0.z + b0.z, (v0.w - mu) * rstd * w0.w + b0.w,
            (v1.x - mu) * rstd * w1.x + b1.x, (v1.y - mu) * rstd * w1.y + b1.y,
            (v1.z - mu) * rstd * w1.z + b1.z, (v1.w - mu) * rstd * w1.w + b1.w };

        float am = 0.0f;
        #pragma unroll
        for (int j = 0; j < 8; ++j) am = fmaxf(am, fabsf(hv[j]));
        #pragma unroll
        for (int off = 1; off < 64; off <<= 1) am = fmaxf(am, __shfl_xor(am, off));
        const float inv = (am > 0.0f) ? (127.0f / am) : 0.0f;
        if (lane == 0) sh[row] = am * (1.0f / 127.0f);

        int qi[8];
        #pragma unroll
        for (int j = 0; j < 8; ++j) qi[j] = __float2int_rn(hv[j] * inv);
        uint2 p = make_uint2(pack4(qi[0], qi[1], qi[2], qi[3]),
                             pack4(qi[4], qi[5], qi[6], qi[7]));
        *(uint2*)(Hq + (size_t)row * DIM + lane * 8) = p;
    } else {                              // ---- E 64-row chunks (per-chunk scale) ----
        const int chunk = b - 2048;                    // 0..127
        const int row   = chunk * 64 + (threadIdx.x >> 2);
        const int off0  = (threadIdx.x & 3) * 128;
        const float* er = embd + (size_t)row * DIM + off0;

        float4 v[32];
        float am = 0.0f;
        #pragma unroll
        for (int j = 0; j < 32; ++j) {
            v[j] = *(const float4*)(er + j * 4);
            am = fmaxf(am, fmaxf(fmaxf(fabsf(v[j].x), fabsf(v[j].y)),
                                 fmaxf(fabsf(v[j].z), fabsf(v[j].w))));
        }
        #pragma unroll
        for (int off = 1; off < 64; off <<= 1) am = fmaxf(am, __shfl_xor(am, off));
        if (lane == 0) red[w] = am;
        __syncthreads();
        am = fmaxf(fmaxf(red[0], red[1]), fmaxf(red[2], red[3]));

        const float inv = (am > 0.0f) ? (127.0f / am) : 0.0f;
        if (threadIdx.x == 0) se[chunk] = am * (1.0f / 127.0f);

        u8* out = Eq + (size_t)row * DIM + off0;
        #pragma unroll
        for (int j = 0; j < 32; j += 4) {
            uint4 o;
            o.x = pack4(__float2int_rn(v[j+0].x*inv), __float2int_rn(v[j+0].y*inv),
                        __float2int_rn(v[j+0].z*inv), __float2int_rn(v[j+0].w*inv));
            o.y = pack4(__float2int_rn(v[j+1].x*inv), __float2int_rn(v[j+1].y*inv),
                        __float2int_rn(v[j+1].z*inv), __float2int_rn(v[j+1].w*inv));
            o.z = pack4(__float2int_rn(v[j+2].x*inv), __float2int_rn(v[j+2].y*inv),
                        __float2int_rn(v[j+2].z*inv), __float2int_rn(v[j+2].w*inv));
            o.w = pack4(__float2int_rn(v[j+3].x*inv), __float2int_rn(v[j+3].y*inv),
                        __float2int_rn(v[j+3].z*inv), __float2int_rn(v[j+3].w*inv));
            *(uint4*)(out + j * 4) = o;
        }
    }
}

// ---------- Kernel 2: R10 GEMM + phase-staggered K order, no setprio ----
// Exact R10 skeleton (256x128 i8, 3-slot ring 2-deep vmcnt(12), i32 argmax).
// Change 1: odd-bid blocks traverse K-tiles as pos^4 (4,5,6,7,0,1,2,3) so the
// two co-resident blocks' MFMA bursts on each SIMD interleave instead of
// colliding in phase (integer accumulation is order-exact; ring slots are
// position-based so all staging/vmcnt invariants are unchanged).
// Change 2: setprio removed (m190: harmful in lockstep-barrier GEMM).
__global__ __launch_bounds__(256, 2) void gemm_argmax_kernel(
    const u8* __restrict__ Hq, const u8* __restrict__ Eq,
    const float* __restrict__ sh, const float* __restrict__ se,
    float* __restrict__ pval, int* __restrict__ pidx)
{
    __shared__ __align__(16) u8 As[3][BM * BK];   // 3 x 16 KB
    __shared__ __align__(16) u8 Bs[3][BN * BK];   // 3 x 8 KB

    const int tid  = threadIdx.x;
    const int w    = tid >> 6;
    const int lane = tid & 63;
    const int r_   = lane & 15;
    const int g    = lane >> 4;
    const int wr   = w >> 1;          // row half (0,1) -> 128 rows
    const int wc   = w & 1;           // col half (0,1) -> 64 cols

    // T1: XCD map. xcd = bid&7 owns 4 row-panels x all 64 col-tiles, col-major.
    const int bid  = blockIdx.x;
    const int trow = ((bid & 7) << 2) | ((bid >> 3) & 3);   // 0..31
    const int tcol = bid >> 5;                              // 0..63
    const int r0 = trow * BM;
    const int n0 = tcol * BN;

    // phase stagger: adjacent bids co-reside on a CU; odd blocks rotate K order
    const int stag = (bid & 1) << 2;   // XOR on tile index: 0 or 4

    // staging geometry (T2 swizzle byte^=((row>>1)&3)<<4, pre-swizzled source)
    const int da0 = (w * 4 + 0) * 16 + (lane >> 2);
    const int da1 = (w * 4 + 1) * 16 + (lane >> 2);
    const int da2 = (w * 4 + 2) * 16 + (lane >> 2);
    const int da3 = (w * 4 + 3) * 16 + (lane >> 2);
    const int db0 = (w * 2 + 0) * 16 + (lane >> 2);
    const int db1 = (w * 2 + 1) * 16 + (lane >> 2);
    const int lc  = (lane & 3) * 16;
    const u8* sA0 = Hq + (size_t)(r0 + da0) * DIM + (lc ^ (((da0 >> 1) & 3) << 4));
    const u8* sA1 = Hq + (size_t)(r0 + da1) * DIM + (lc ^ (((da1 >> 1) & 3) << 4));
    const u8* sA2 = Hq + (size_t)(r0 + da2) * DIM + (lc ^ (((da2 >> 1) & 3) << 4));
    const u8* sA3 = Hq + (size_t)(r0 + da3) * DIM + (lc ^ (((da3 >> 1) & 3) << 4));
    const u8* sB0 = Eq + (size_t)(n0 + db0) * DIM + (lc ^ (((db0 >> 1) & 3) << 4));
    const u8* sB1 = Eq + (size_t)(n0 + db1) * DIM + (lc ^ (((db1 >> 1) & 3) << 4));
    const int ua0 = (w * 4 + 0) * 1024, ua1 = (w * 4 + 1) * 1024;
    const int ua2 = (w * 4 + 2) * 1024, ua3 = (w * 4 + 3) * 1024;
    const int ub0 = (w * 2 + 0) * 1024, ub1 = (w * 2 + 1) * 1024;

    // swizzled ds_read bases (byte offsets within a slot); rows are 64 B.
    const int swz   = ((r_ >> 1) & 3) << 4;
    const int abase = (wr * 128 + r_) * 64 + ((g * 16) ^ swz);   // + m*1024
    const int bbase = (wc * 64  + r_) * 64 + ((g * 16) ^ swz);   // + n*1024

    i32x4 acc[8][4];
    #pragma unroll
    for (int m = 0; m < 8; ++m)
        #pragma unroll
        for (int n = 0; n < 4; ++n) acc[m][n] = (i32x4){0, 0, 0, 0};

#define STAGE(T, SL) do {                                           \
        const int _ko = (T) * BK;                                   \
        gload_lds16(sA0 + _ko, &As[SL][ua0]);                       \
        gload_lds16(sA1 + _ko, &As[SL][ua1]);                       \
        gload_lds16(sA2 + _ko, &As[SL][ua2]);                       \
        gload_lds16(sA3 + _ko, &As[SL][ua3]);                       \
        gload_lds16(sB0 + _ko, &Bs[SL][ub0]);                       \
        gload_lds16(sB1 + _ko, &Bs[SL][ub1]);                       \
    } while (0)
#define MF(M, N, AV, BV) \
        acc[M][N] = __builtin_amdgcn_mfma_i32_16x16x64_i8(AV, BV, acc[M][N], 0, 0, 0)

#define K_TILE(SL, STG, VMSTR) do {                                 \
        STG;                                                        \
        asm volatile("s_waitcnt vmcnt(" VMSTR ")" ::: "memory");    \
        __builtin_amdgcn_s_barrier();                               \
        const char* Ab = (const char*)&As[SL][0];                   \
        const char* Bb = (const char*)&Bs[SL][0];                   \
        i32x4 a0 = *(const i32x4*)(Ab + abase + 0 * 1024);          \
        i32x4 a1 = *(const i32x4*)(Ab + abase + 1 * 1024);          \
        i32x4 a2 = *(const i32x4*)(Ab + abase + 2 * 1024);          \
        i32x4 a3 = *(const i32x4*)(Ab + abase + 3 * 1024);          \
        i32x4 a4 = *(const i32x4*)(Ab + abase + 4 * 1024);          \
        i32x4 a5 = *(const i32x4*)(Ab + abase + 5 * 1024);          \
        i32x4 a6 = *(const i32x4*)(Ab + abase + 6 * 1024);          \
        i32x4 a7 = *(const i32x4*)(Ab + abase + 7 * 1024);          \
        i32x4 b0 = *(const i32x4*)(Bb + bbase + 0 * 1024);          \
        i32x4 b1 = *(const i32x4*)(Bb + bbase + 1 * 1024);          \
        i32x4 b2 = *(const i32x4*)(Bb + bbase + 2 * 1024);          \
        i32x4 b3 = *(const i32x4*)(Bb + bbase + 3 * 1024);          \
        MF(0, 0, a0, b0); MF(0, 1, a0, b1); MF(0, 2, a0, b2); MF(0, 3, a0, b3); \
        MF(1, 0, a1, b0); MF(1, 1, a1, b1); MF(1, 2, a1, b2); MF(1, 3, a1, b3); \
        MF(2, 0, a2, b0); MF(2, 1, a2, b1); MF(2, 2, a2, b2); MF(2, 3, a2, b3); \
        MF(3, 0, a3, b0); MF(3, 1, a3, b1); MF(3, 2, a3, b2); MF(3, 3, a3, b3); \
        MF(4, 0, a4, b0); MF(4, 1, a4, b1); MF(4, 2, a4, b2); MF(4, 3, a4, b3); \
        MF(5, 0, a5, b0); MF(5, 1, a5, b1); MF(5, 2, a5, b2); MF(5, 3, a5, b3); \
        MF(6, 0, a6, b0); MF(6, 1, a6, b1); MF(6, 2, a6, b2); MF(6, 3, a6, b3); \
        MF(7, 0, a7, b0); MF(7, 1, a7, b1); MF(7, 2, a7, b2); MF(7, 3, a7, b3); \
        __builtin_amdgcn_s_barrier();                               \
    } while (0)

    // prologue: positions 0,1 staged (tiles stag^0, stag^1); 2 tiles in flight
    STAGE(0 ^ stag, 0);
    STAGE(1 ^ stag, 1);

    K_TILE(0, STAGE(2 ^ stag, 2), "12");   // pos 0
    K_TILE(1, STAGE(3 ^ stag, 0), "12");   // pos 1
    K_TILE(2, STAGE(4 ^ stag, 1), "12");   // pos 2
    K_TILE(0, STAGE(5 ^ stag, 2), "12");   // pos 3
    K_TILE(1, STAGE(6 ^ stag, 0), "12");   // pos 4
    K_TILE(2, STAGE(7 ^ stag, 1), "12");   // pos 5
    K_TILE(0, , "6");                      // pos 6
    K_TILE(1, , "0");                      // pos 7

#undef K_TILE
#undef MF
#undef STAGE

    // ---- epilogue: pure-i32 packed-key top-2 per (row, 64-col chunk) ----
    const int cb    = n0 + wc * 64;
    const float se_ch = se[tcol * 2 + wc];
    #pragma unroll
    for (int m = 0; m < 8; ++m) {
        const float4 sc4 = *(const float4*)&sh[r0 + wr * 128 + m * 16 + g * 4];
        #pragma unroll
        for (int reg = 0; reg < 4; ++reg) {
            int ka = (acc[m][0][reg] << 7) | (63 - r_);
            int kb = (acc[m][1][reg] << 7) | (47 - r_);
            int kc = (acc[m][2][reg] << 7) | (31 - r_);
            int kd = (acc[m][3][reg] << 7) | (15 - r_);
            int m1 = max(ka, kb), n1 = min(ka, kb);
            int m2 = max(kc, kd), n2 = min(kc, kd);
            int k1 = max(m1, m2);
            int k2 = max(min(m1, m2), max(n1, n2));
            #pragma unroll
            for (int off = 1; off < 16; off <<= 1) {
                int b1 = __shfl_xor(k1, off);
                int b2 = __shfl_xor(k2, off);
                k2 = max(max(k2, b2), min(k1, b1));
                k1 = max(k1, b1);
            }
            if (r_ == 0) {
                const float sc = (reg == 0) ? sc4.x : (reg == 1) ? sc4.y
                                 : (reg == 2) ? sc4.z : sc4.w;
                const int row = r0 + wr * 128 + m * 16 + g * 4 + reg;
                const size_t base = (size_t)row * 256 + (tcol * 2 + wc) * 2;
                pval[base]     = (float)(k1 >> 7) * (sc * se_ch);
                pval[base + 1] = (float)(k2 >> 7) * (sc * se_ch);
                pidx[base]     = cb + 63 - (k1 & 63);
                pidx[base + 1] = cb + 63 - (k2 & 63);
            }
        }
    }
}

// ---------- Kernel 3: exact fp32 re-check of candidates + gather ----------
__global__ __launch_bounds__(256) void finalize_kernel(
    const float* __restrict__ x, const float* __restrict__ lw,
    const float* __restrict__ lb, const float* __restrict__ embd,
    const float2* __restrict__ stats,
    const float* __restrict__ pval, const int* __restrict__ pidx,
    float* __restrict__ outq, float* __restrict__ outi)
{
    const int w    = threadIdx.x >> 6;
    const int lane = threadIdx.x & 63;
    const int row  = blockIdx.x * 4 + w;

    const float4 cv = *(const float4*)&pval[(size_t)row * 256 + lane * 4];
    const int4   ci = *(const int4*)  &pidx[(size_t)row * 256 + lane * 4];
    float vv[4] = { cv.x, cv.y, cv.z, cv.w };
    int   ii[4] = { ci.x, ci.y, ci.z, ci.w };

    float M = fmaxf(fmaxf(vv[0], vv[1]), fmaxf(vv[2], vv[3]));
    #pragma unroll
    for (int off = 1; off < 64; off <<= 1) M = fmaxf(M, __shfl_xor(M, off));
    const float T = M - MARGIN;

    const float2 st = stats[row];
    const float mu = st.x, rstd = st.y;
    const float* xr = x + (size_t)row * DIM + lane * 8;
    float4 x0 = *(const float4*)(xr);
    float4 x1 = *(const float4*)(xr + 4);
    float4 w0 = *(const float4*)(lw + lane * 8);
    float4 w1 = *(const float4*)(lw + lane * 8 + 4);
    float4 b0 = *(const float4*)(lb + lane * 8);
    float4 b1 = *(const float4*)(lb + lane * 8 + 4);
    float h[8] = {
        (x0.x - mu) * rstd * w0.x + b0.x, (x0.y - mu) * rstd * w0.y + b0.y,
        (x0.z - mu) * rstd * w0.z + b0.z, (x0.w - mu) * rstd * w0.w + b0.w,
        (x1.x - mu) * rstd * w1.x + b1.x, (x1.y - mu) * rstd * w1.y + b1.y,
        (x1.z - mu) * rstd * w1.z + b1.z, (x1.w - mu) * rstd * w1.w + b1.w };

    float bestv = -3.4e38f; int besti = 0x7fffffff;
    #pragma unroll
    for (int s = 0; s < 4; ++s) {
        unsigned long long msk = __ballot(vv[s] >= T);
        while (msk) {
            const int L = __ffsll(msk) - 1;
            msk &= msk - 1;
            const int cand = __shfl(ii[s], L);
            const float* er = embd + (size_t)cand * DIM + lane * 8;
            float4 e0 = *(const float4*)er;
            float4 e1 = *(const float4*)(er + 4);
            float d = h[0]*e0.x + h[1]*e0.y + h[2]*e0.z + h[3]*e0.w
                    + h[4]*e1.x + h[5]*e1.y + h[6]*e1.z + h[7]*e1.w;
            #pragma unroll
            for (int off = 1; off < 64; off <<= 1) d += __shfl_xor(d, off);
            if (d > bestv || (d == bestv && cand < besti)) { bestv = d; besti = cand; }
        }
    }

    const float* er = embd + (size_t)besti * DIM + lane * 8;
    float4 q0 = *(const float4*)er;
    float4 q1 = *(const float4*)(er + 4);
    float* qr = outq + (size_t)row * DIM + lane * 8;
    *(float4*)(qr)     = q0;
    *(float4*)(qr + 4) = q1;
    if (lane == 0) outi[row] = (float)besti;
}

extern "C" void kernel_launch(void* const* d_in, const int* in_sizes, int n_in,
                              void* d_out, int out_size, void* d_ws, size_t ws_size,
                              hipStream_t stream) {
    const float* x    = (const float*)d_in[0];
    const float* lnw  = (const float*)d_in[1];
    const float* lnb  = (const float*)d_in[2];
    const float* embd = (const float*)d_in[3];

    float* outq = (float*)d_out;
    float* outi = outq + (size_t)ROWS * DIM;

    char* ws = (char*)d_ws;
    float2* stats = (float2*)ws;                                  // 64 KiB
    float*  sh    = (float*)(ws + (1 << 16));                     // 32 KiB
    float*  se    = (float*)(ws + (1 << 16) + (1 << 15));         // 512 B used
    u8*     Hq    = (u8*)(ws + (1 << 17));                        // 4 MiB
    u8*     Eq    = (u8*)(ws + (1 << 17) + (4 << 20));            // 4 MiB
    float*  pval  = (float*)(ws + (1 << 17) + (8 << 20));         // 8 MiB
    int*    pidx  = (int*)  (ws + (1 << 17) + (16 << 20));        // 8 MiB

    prep_kernel<<<2176, 256, 0, stream>>>(x, lnw, lnb, embd, stats, sh, se, Hq, Eq);

    gemm_argmax_kernel<<<2048, 256, 0, stream>>>(Hq, Eq, sh, se, pval, pidx);

    finalize_kernel<<<ROWS / 4, 256, 0, stream>>>(x, lnw, lnb, embd, stats,
                                                  pval, pidx, outq, outi);
}

// Round 18
// 105.883 us; speedup vs baseline: 1.2811x; 1.0001x over previous
//
#include <hip/hip_runtime.h>
#include <hip/hip_bf16.h>

#define ROWS   8192
#define DIM    512
#define NCODES 8192
#define BM     256
#define BN     128
#define BK     64                     // i8 K-tile
#define NT     (DIM / BK)             // 8 K-tiles
#define MARGIN 3.0f

using i32x4 = __attribute__((ext_vector_type(4))) int;
typedef unsigned char u8;

__device__ __forceinline__ void gload_lds16(const void* g, void* l) {
    __builtin_amdgcn_global_load_lds((const __attribute__((address_space(1))) void*)g,
                                     (__attribute__((address_space(3))) void*)l,
                                     16, 0, 0);
}

__device__ __forceinline__ unsigned int pack4(int a, int b, int c, int d) {
    return (a & 255) | ((b & 255) << 8) | ((c & 255) << 16) | ((unsigned)(d & 255) << 24);
}

// ---------- Kernel 1: LN+quant(H, per-row) | quant(E, per-64-row-chunk) ----------
__global__ __launch_bounds__(256) void prep_kernel(
    const float* __restrict__ x, const float* __restrict__ lw,
    const float* __restrict__ lb, const float* __restrict__ embd,
    float2* __restrict__ stats, float* __restrict__ sh, float* __restrict__ se,
    u8* __restrict__ Hq, u8* __restrict__ Eq)
{
    __shared__ float red[4];
    const int w    = threadIdx.x >> 6;
    const int lane = threadIdx.x & 63;
    const int b    = blockIdx.x;

    if (b < 2048) {                       // ---- H rows (per-row scale) ----
        const int row = b * 4 + w;
        const float* xr = x + (size_t)row * DIM + lane * 8;
        float4 v0 = *(const float4*)(xr);
        float4 v1 = *(const float4*)(xr + 4);
        float s = (v0.x + v0.y) + (v0.z + v0.w) + (v1.x + v1.y) + (v1.z + v1.w);
        float q = v0.x*v0.x + v0.y*v0.y + v0.z*v0.z + v0.w*v0.w
                + v1.x*v1.x + v1.y*v1.y + v1.z*v1.z + v1.w*v1.w;
        #pragma unroll
        for (int off = 1; off < 64; off <<= 1) {
            s += __shfl_xor(s, off);
            q += __shfl_xor(q, off);
        }
        float mu   = s * (1.0f / DIM);
        float var  = q * (1.0f / DIM) - mu * mu;
        float rstd = rsqrtf(var + 1e-5f);
        if (lane == 0) stats[row] = make_float2(mu, rstd);

        float4 w0 = *(const float4*)(lw + lane * 8);
        float4 w1 = *(const float4*)(lw + lane * 8 + 4);
        float4 b0 = *(const float4*)(lb + lane * 8);
        float4 b1 = *(const float4*)(lb + lane * 8 + 4);
        float hv[8] = {
            (v0.x - mu) * rstd * w0.x + b0.x, (v0.y - mu) * rstd * w0.y + b0.y,
            (v0.z - mu) * rstd * w0.z + b0.z, (v0.w - mu) * rstd * w0.w + b0.w,
            (v1.x - mu) * rstd * w1.x + b1.x, (v1.y - mu) * rstd * w1.y + b1.y,
            (v1.z - mu) * rstd * w1.z + b1.z, (v1.w - mu) * rstd * w1.w + b1.w };

        float am = 0.0f;
        #pragma unroll
        for (int j = 0; j < 8; ++j) am = fmaxf(am, fabsf(hv[j]));
        #pragma unroll
        for (int off = 1; off < 64; off <<= 1) am = fmaxf(am, __shfl_xor(am, off));
        const float inv = (am > 0.0f) ? (127.0f / am) : 0.0f;
        if (lane == 0) sh[row] = am * (1.0f / 127.0f);

        int qi[8];
        #pragma unroll
        for (int j = 0; j < 8; ++j) qi[j] = __float2int_rn(hv[j] * inv);
        uint2 p = make_uint2(pack4(qi[0], qi[1], qi[2], qi[3]),
                             pack4(qi[4], qi[5], qi[6], qi[7]));
        *(uint2*)(Hq + (size_t)row * DIM + lane * 8) = p;
    } else {                              // ---- E 64-row chunks (per-chunk scale) ----
        const int chunk = b - 2048;                    // 0..127
        const int row   = chunk * 64 + (threadIdx.x >> 2);
        const int off0  = (threadIdx.x & 3) * 128;
        const float* er = embd + (size_t)row * DIM + off0;

        float4 v[32];
        float am = 0.0f;
        #pragma unroll
        for (int j = 0; j < 32; ++j) {
            v[j] = *(const float4*)(er + j * 4);
            am = fmaxf(am, fmaxf(fmaxf(fabsf(v[j].x), fabsf(v[j].y)),
                                 fmaxf(fabsf(v[j].z), fabsf(v[j].w))));
        }
        #pragma unroll
        for (int off = 1; off < 64; off <<= 1) am = fmaxf(am, __shfl_xor(am, off));
        if (lane == 0) red[w] = am;
        __syncthreads();
        am = fmaxf(fmaxf(red[0], red[1]), fmaxf(red[2], red[3]));

        const float inv = (am > 0.0f) ? (127.0f / am) : 0.0f;
        if (threadIdx.x == 0) se[chunk] = am * (1.0f / 127.0f);

        u8* out = Eq + (size_t)row * DIM + off0;
        #pragma unroll
        for (int j = 0; j < 32; j += 4) {
            uint4 o;
            o.x = pack4(__float2int_rn(v[j+0].x*inv), __float2int_rn(v[j+0].y*inv),
                        __float2int_rn(v[j+0].z*inv), __float2int_rn(v[j+0].w*inv));
            o.y = pack4(__float2int_rn(v[j+1].x*inv), __float2int_rn(v[j+1].y*inv),
                        __float2int_rn(v[j+1].z*inv), __float2int_rn(v[j+1].w*inv));
            o.z = pack4(__float2int_rn(v[j+2].x*inv), __float2int_rn(v[j+2].y*inv),
                        __float2int_rn(v[j+2].z*inv), __float2int_rn(v[j+2].w*inv));
            o.w = pack4(__float2int_rn(v[j+3].x*inv), __float2int_rn(v[j+3].y*inv),
                        __float2int_rn(v[j+3].z*inv), __float2int_rn(v[j+3].w*inv));
            *(uint4*)(out + j * 4) = o;
        }
    }
}

// ---------- Kernel 2: one barrier per K-tile, STAGE issued POST-barrier ----
// R17's race fixed: STAGE(k+2) now sits AFTER barrier k, so a wave issues it
// only once ALL waves passed barrier k — which requires their body-(k-1)
// ds_reads of slot (k-1)%3 (= the stage target (k+2)%3) to be complete (lgkm
// data-dep precedes last MFMA precedes barrier arrival). Within body k: reads
// slot k%3, writes (k-1)%3 — disjoint. Visibility: at body k's vmcnt the
// newest 6 outstanding are STAGE(k+1) -> vmcnt(6) proves STAGE(k) landed
// per-wave; the barrier extends it block-wide. Bodies 0-6 vmcnt(6), body 7
// vmcnt(0). 8 barriers per block (vs R16's 16).
__global__ __launch_bounds__(256, 2) void gemm_argmax_kernel(
    const u8* __restrict__ Hq, const u8* __restrict__ Eq,
    const float* __restrict__ sh, const float* __restrict__ se,
    float* __restrict__ pval, int* __restrict__ pidx)
{
    __shared__ __align__(16) u8 As[3][BM * BK];   // 3 x 16 KB
    __shared__ __align__(16) u8 Bs[3][BN * BK];   // 3 x 8 KB

    const int tid  = threadIdx.x;
    const int w    = tid >> 6;
    const int lane = tid & 63;
    const int r_   = lane & 15;
    const int g    = lane >> 4;
    const int wr   = w >> 1;          // row half (0,1) -> 128 rows
    const int wc   = w & 1;           // col half (0,1) -> 64 cols

    // T1: XCD map. xcd = bid&7 owns 4 row-panels x all 64 col-tiles, col-major.
    const int bid  = blockIdx.x;
    const int trow = ((bid & 7) << 2) | ((bid >> 3) & 3);   // 0..31
    const int tcol = bid >> 5;                              // 0..63
    const int r0 = trow * BM;
    const int n0 = tcol * BN;

    // phase stagger: adjacent bids co-reside on a CU; odd blocks rotate K order
    const int stag = (bid & 1) << 2;   // XOR on tile index: 0 or 4

    // staging geometry (T2 swizzle byte^=((row>>1)&3)<<4, pre-swizzled source)
    const int da0 = (w * 4 + 0) * 16 + (lane >> 2);
    const int da1 = (w * 4 + 1) * 16 + (lane >> 2);
    const int da2 = (w * 4 + 2) * 16 + (lane >> 2);
    const int da3 = (w * 4 + 3) * 16 + (lane >> 2);
    const int db0 = (w * 2 + 0) * 16 + (lane >> 2);
    const int db1 = (w * 2 + 1) * 16 + (lane >> 2);
    const int lc  = (lane & 3) * 16;
    const u8* sA0 = Hq + (size_t)(r0 + da0) * DIM + (lc ^ (((da0 >> 1) & 3) << 4));
    const u8* sA1 = Hq + (size_t)(r0 + da1) * DIM + (lc ^ (((da1 >> 1) & 3) << 4));
    const u8* sA2 = Hq + (size_t)(r0 + da2) * DIM + (lc ^ (((da2 >> 1) & 3) << 4));
    const u8* sA3 = Hq + (size_t)(r0 + da3) * DIM + (lc ^ (((da3 >> 1) & 3) << 4));
    const u8* sB0 = Eq + (size_t)(n0 + db0) * DIM + (lc ^ (((db0 >> 1) & 3) << 4));
    const u8* sB1 = Eq + (size_t)(n0 + db1) * DIM + (lc ^ (((db1 >> 1) & 3) << 4));
    const int ua0 = (w * 4 + 0) * 1024, ua1 = (w * 4 + 1) * 1024;
    const int ua2 = (w * 4 + 2) * 1024, ua3 = (w * 4 + 3) * 1024;
    const int ub0 = (w * 2 + 0) * 1024, ub1 = (w * 2 + 1) * 1024;

    // swizzled ds_read bases (byte offsets within a slot); rows are 64 B.
    const int swz   = ((r_ >> 1) & 3) << 4;
    const int abase = (wr * 128 + r_) * 64 + ((g * 16) ^ swz);   // + m*1024
    const int bbase = (wc * 64  + r_) * 64 + ((g * 16) ^ swz);   // + n*1024

    i32x4 acc[8][4];
    #pragma unroll
    for (int m = 0; m < 8; ++m)
        #pragma unroll
        for (int n = 0; n < 4; ++n) acc[m][n] = (i32x4){0, 0, 0, 0};

#define STAGE(T, SL) do {                                           \
        const int _ko = (T) * BK;                                   \
        gload_lds16(sA0 + _ko, &As[SL][ua0]);                       \
        gload_lds16(sA1 + _ko, &As[SL][ua1]);                       \
        gload_lds16(sA2 + _ko, &As[SL][ua2]);                       \
        gload_lds16(sA3 + _ko, &As[SL][ua3]);                       \
        gload_lds16(sB0 + _ko, &Bs[SL][ub0]);                       \
        gload_lds16(sB1 + _ko, &Bs[SL][ub1]);                       \
    } while (0)
#define MF(M, N, AV, BV) \
        acc[M][N] = __builtin_amdgcn_mfma_i32_16x16x64_i8(AV, BV, acc[M][N], 0, 0, 0)

#define K_TILE(SL, STG, VMSTR) do {                                 \
        asm volatile("s_waitcnt vmcnt(" VMSTR ")" ::: "memory");    \
        __builtin_amdgcn_s_barrier();                               \
        STG;                                                        \
        const char* Ab = (const char*)&As[SL][0];                   \
        const char* Bb = (const char*)&Bs[SL][0];                   \
        i32x4 a0 = *(const i32x4*)(Ab + abase + 0 * 1024);          \
        i32x4 a1 = *(const i32x4*)(Ab + abase + 1 * 1024);          \
        i32x4 a2 = *(const i32x4*)(Ab + abase + 2 * 1024);          \
        i32x4 a3 = *(const i32x4*)(Ab + abase + 3 * 1024);          \
        i32x4 a4 = *(const i32x4*)(Ab + abase + 4 * 1024);          \
        i32x4 a5 = *(const i32x4*)(Ab + abase + 5 * 1024);          \
        i32x4 a6 = *(const i32x4*)(Ab + abase + 6 * 1024);          \
        i32x4 a7 = *(const i32x4*)(Ab + abase + 7 * 1024);          \
        i32x4 b0 = *(const i32x4*)(Bb + bbase + 0 * 1024);          \
        i32x4 b1 = *(const i32x4*)(Bb + bbase + 1 * 1024);          \
        i32x4 b2 = *(const i32x4*)(Bb + bbase + 2 * 1024);          \
        i32x4 b3 = *(const i32x4*)(Bb + bbase + 3 * 1024);          \
        MF(0, 0, a0, b0); MF(0, 1, a0, b1); MF(0, 2, a0, b2); MF(0, 3, a0, b3); \
        MF(1, 0, a1, b0); MF(1, 1, a1, b1); MF(1, 2, a1, b2); MF(1, 3, a1, b3); \
        MF(2, 0, a2, b0); MF(2, 1, a2, b1); MF(2, 2, a2, b2); MF(2, 3, a2, b3); \
        MF(3, 0, a3, b0); MF(3, 1, a3, b1); MF(3, 2, a3, b2); MF(3, 3, a3, b3); \
        MF(4, 0, a4, b0); MF(4, 1, a4, b1); MF(4, 2, a4, b2); MF(4, 3, a4, b3); \
        MF(5, 0, a5, b0); MF(5, 1, a5, b1); MF(5, 2, a5, b2); MF(5, 3, a5, b3); \
        MF(6, 0, a6, b0); MF(6, 1, a6, b1); MF(6, 2, a6, b2); MF(6, 3, a6, b3); \
        MF(7, 0, a7, b0); MF(7, 1, a7, b1); MF(7, 2, a7, b2); MF(7, 3, a7, b3); \
    } while (0)

    // prologue: positions 0,1 staged (tiles stag^0, stag^1); 12 loads in flight
    STAGE(0 ^ stag, 0);
    STAGE(1 ^ stag, 1);

    K_TILE(0, STAGE(2 ^ stag, 2), "6");   // pos 0
    K_TILE(1, STAGE(3 ^ stag, 0), "6");   // pos 1
    K_TILE(2, STAGE(4 ^ stag, 1), "6");   // pos 2
    K_TILE(0, STAGE(5 ^ stag, 2), "6");   // pos 3
    K_TILE(1, STAGE(6 ^ stag, 0), "6");   // pos 4
    K_TILE(2, STAGE(7 ^ stag, 1), "6");   // pos 5
    K_TILE(0, , "6");                     // pos 6
    K_TILE(1, , "0");                     // pos 7

#undef K_TILE
#undef MF
#undef STAGE

    // ---- epilogue: pure-i32 packed-key top-2 per (row, 64-col chunk) ----
    const int cb    = n0 + wc * 64;
    const float se_ch = se[tcol * 2 + wc];
    #pragma unroll
    for (int m = 0; m < 8; ++m) {
        const float4 sc4 = *(const float4*)&sh[r0 + wr * 128 + m * 16 + g * 4];
        #pragma unroll
        for (int reg = 0; reg < 4; ++reg) {
            int ka = (acc[m][0][reg] << 7) | (63 - r_);
            int kb = (acc[m][1][reg] << 7) | (47 - r_);
            int kc = (acc[m][2][reg] << 7) | (31 - r_);
            int kd = (acc[m][3][reg] << 7) | (15 - r_);
            int m1 = max(ka, kb), n1 = min(ka, kb);
            int m2 = max(kc, kd), n2 = min(kc, kd);
            int k1 = max(m1, m2);
            int k2 = max(min(m1, m2), max(n1, n2));
            #pragma unroll
            for (int off = 1; off < 16; off <<= 1) {
                int b1 = __shfl_xor(k1, off);
                int b2 = __shfl_xor(k2, off);
                k2 = max(max(k2, b2), min(k1, b1));
                k1 = max(k1, b1);
            }
            if (r_ == 0) {
                const float sc = (reg == 0) ? sc4.x : (reg == 1) ? sc4.y
                                 : (reg == 2) ? sc4.z : sc4.w;
                const int row = r0 + wr * 128 + m * 16 + g * 4 + reg;
                const size_t base = (size_t)row * 256 + (tcol * 2 + wc) * 2;
                pval[base]     = (float)(k1 >> 7) * (sc * se_ch);
                pval[base + 1] = (float)(k2 >> 7) * (sc * se_ch);
                pidx[base]     = cb + 63 - (k1 & 63);
                pidx[base + 1] = cb + 63 - (k2 & 63);
            }
        }
    }
}

// ---------- Kernel 3: exact fp32 re-check of candidates + gather ----------
__global__ __launch_bounds__(256) void finalize_kernel(
    const float* __restrict__ x, const float* __restrict__ lw,
    const float* __restrict__ lb, const float* __restrict__ embd,
    const float2* __restrict__ stats,
    const float* __restrict__ pval, const int* __restrict__ pidx,
    float* __restrict__ outq, float* __restrict__ outi)
{
    const int w    = threadIdx.x >> 6;
    const int lane = threadIdx.x & 63;
    const int row  = blockIdx.x * 4 + w;

    const float4 cv = *(const float4*)&pval[(size_t)row * 256 + lane * 4];
    const int4   ci = *(const int4*)  &pidx[(size_t)row * 256 + lane * 4];
    float vv[4] = { cv.x, cv.y, cv.z, cv.w };
    int   ii[4] = { ci.x, ci.y, ci.z, ci.w };

    float M = fmaxf(fmaxf(vv[0], vv[1]), fmaxf(vv[2], vv[3]));
    #pragma unroll
    for (int off = 1; off < 64; off <<= 1) M = fmaxf(M, __shfl_xor(M, off));
    const float T = M - MARGIN;

    const float2 st = stats[row];
    const float mu = st.x, rstd = st.y;
    const float* xr = x + (size_t)row * DIM + lane * 8;
    float4 x0 = *(const float4*)(xr);
    float4 x1 = *(const float4*)(xr + 4);
    float4 w0 = *(const float4*)(lw + lane * 8);
    float4 w1 = *(const float4*)(lw + lane * 8 + 4);
    float4 b0 = *(const float4*)(lb + lane * 8);
    float4 b1 = *(const float4*)(lb + lane * 8 + 4);
    float h[8] = {
        (x0.x - mu) * rstd * w0.x + b0.x, (x0.y - mu) * rstd * w0.y + b0.y,
        (x0.z - mu) * rstd * w0.z + b0.z, (x0.w - mu) * rstd * w0.w + b0.w,
        (x1.x - mu) * rstd * w1.x + b1.x, (x1.y - mu) * rstd * w1.y + b1.y,
        (x1.z - mu) * rstd * w1.z + b1.z, (x1.w - mu) * rstd * w1.w + b1.w };

    float bestv = -3.4e38f; int besti = 0x7fffffff;
    #pragma unroll
    for (int s = 0; s < 4; ++s) {
        unsigned long long msk = __ballot(vv[s] >= T);
        while (msk) {
            const int L = __ffsll(msk) - 1;
            msk &= msk - 1;
            const int cand = __shfl(ii[s], L);
            const float* er = embd + (size_t)cand * DIM + lane * 8;
            float4 e0 = *(const float4*)er;
            float4 e1 = *(const float4*)(er + 4);
            float d = h[0]*e0.x + h[1]*e0.y + h[2]*e0.z + h[3]*e0.w
                    + h[4]*e1.x + h[5]*e1.y + h[6]*e1.z + h[7]*e1.w;
            #pragma unroll
            for (int off = 1; off < 64; off <<= 1) d += __shfl_xor(d, off);
            if (d > bestv || (d == bestv && cand < besti)) { bestv = d; besti = cand; }
        }
    }

    const float* er = embd + (size_t)besti * DIM + lane * 8;
    float4 q0 = *(const float4*)er;
    float4 q1 = *(const float4*)(er + 4);
    float* qr = outq + (size_t)row * DIM + lane * 8;
    *(float4*)(qr)     = q0;
    *(float4*)(qr + 4) = q1;
    if (lane == 0) outi[row] = (float)besti;
}

extern "C" void kernel_launch(void* const* d_in, const int* in_sizes, int n_in,
                              void* d_out, int out_size, void* d_ws, size_t ws_size,
                              hipStream_t stream) {
    const float* x    = (const float*)d_in[0];
    const float* lnw  = (const float*)d_in[1];
    const float* lnb  = (const float*)d_in[2];
    const float* embd = (const float*)d_in[3];

    float* outq = (float*)d_out;
    float* outi = outq + (size_t)ROWS * DIM;

    char* ws = (char*)d_ws;
    float2* stats = (float2*)ws;                                  // 64 KiB
    float*  sh    = (float*)(ws + (1 << 16));                     // 32 KiB
    float*  se    = (float*)(ws + (1 << 16) + (1 << 15));         // 512 B used
    u8*     Hq    = (u8*)(ws + (1 << 17));                        // 4 MiB
    u8*     Eq    = (u8*)(ws + (1 << 17) + (4 << 20));            // 4 MiB
    float*  pval  = (float*)(ws + (1 << 17) + (8 << 20));         // 8 MiB
    int*    pidx  = (int*)  (ws + (1 << 17) + (16 << 20));        // 8 MiB

    prep_kernel<<<2176, 256, 0, stream>>>(x, lnw, lnb, embd, stats, sh, se, Hq, Eq);

    gemm_argmax_kernel<<<2048, 256, 0, stream>>>(Hq, Eq, sh, se, pval, pidx);

    finalize_kernel<<<ROWS / 4, 256, 0, stream>>>(x, lnw, lnb, embd, stats,
                                                  pval, pidx, outq, outi);
}